// Round 14
// baseline (332.726 us; speedup 1.0000x reference)
//
#include <hip/hip_runtime.h>
#include <math.h>

typedef __attribute__((ext_vector_type(8))) short short8;
typedef __attribute__((ext_vector_type(4))) float f32x4;
typedef __attribute__((ext_vector_type(4))) _Float16 half4;
typedef __attribute__((ext_vector_type(8))) _Float16 half8;

#define N_SUBN   20000
#define E_EDGES  400000
#define R_REL    16
#define H_DIM    256
#define NBINS    (N_SUBN * R_REL)          // 320000 (dst,rel) buckets
#define SCAN_CHUNK 2048
#define NSCAN_BLOCKS ((NBINS + SCAN_CHUNK - 1) / SCAN_CHUNK)   // 157
#define NPAIRS   4096
#define TILE_N   32
#define NT_BLOCKS (N_SUBN / TILE_N)                            // 625 exact
#define D2       512
#define ECAP     1024                      // LDS edge-cache capacity (avg ~640/block)

// ---- bf16 hi/lo split helpers (RNE) ----
__device__ __forceinline__ ushort f2bf(float x) {
    uint u = __float_as_uint(x);
    u += 0x7fffu + ((u >> 16) & 1u);
    return (ushort)(u >> 16);
}
__device__ __forceinline__ float bf2f(ushort h) {
    return __uint_as_float(((uint)h) << 16);
}

// ---------------- CSR build over bin = dst*R + etype ----------------
__global__ void k_count(const int* __restrict__ dst, const int* __restrict__ ety,
                        int* __restrict__ cnt) {
    int e = blockIdx.x * 256 + threadIdx.x;
    if (e < E_EDGES) atomicAdd(&cnt[dst[e] * R_REL + ety[e]], 1);
}

__global__ void k_scan1(int* __restrict__ data, int* __restrict__ bs) {
    __shared__ int ts[256];
    int base = blockIdx.x * SCAN_CHUNK + threadIdx.x * 8;
    int v[8]; int s = 0;
#pragma unroll
    for (int j = 0; j < 8; j++) {
        int idx = base + j;
        v[j] = (idx < NBINS) ? data[idx] : 0;
        s += v[j];
    }
    ts[threadIdx.x] = s;
    __syncthreads();
    for (int off = 1; off < 256; off <<= 1) {
        int add = (threadIdx.x >= (unsigned)off) ? ts[threadIdx.x - off] : 0;
        __syncthreads();
        ts[threadIdx.x] += add;
        __syncthreads();
    }
    int excl = ts[threadIdx.x] - s;
    if (threadIdx.x == 255) bs[blockIdx.x] = ts[255];
    int run = excl;
#pragma unroll
    for (int j = 0; j < 8; j++) {
        int idx = base + j;
        if (idx < NBINS) data[idx] = run;
        run += v[j];
    }
}

__global__ void k_scan2(int* __restrict__ bs) {
    __shared__ int ls[NSCAN_BLOCKS];
    if (threadIdx.x < NSCAN_BLOCKS) ls[threadIdx.x] = bs[threadIdx.x];
    __syncthreads();
    if (threadIdx.x == 0) {
        int run = 0;
        for (int i = 0; i < NSCAN_BLOCKS; i++) { int t = ls[i]; ls[i] = run; run += t; }
    }
    __syncthreads();
    if (threadIdx.x < NSCAN_BLOCKS) bs[threadIdx.x] = ls[threadIdx.x];
}

__global__ void k_scan3(int* __restrict__ data, const int* __restrict__ bs) {
    int idx = blockIdx.x * 256 + threadIdx.x;
    if (idx < NBINS) data[idx] = data[idx] + bs[idx / SCAN_CHUNK];
}

// scatter increments segend in place: post-scatter segend[bin] = END of bin,
// beg(bin) = (bin==0) ? 0 : segend[bin-1]. Edge packed: (src<<17) | norm_q17.
__global__ void k_scatter(const int* __restrict__ src, const int* __restrict__ dst,
                          const int* __restrict__ ety, const float* __restrict__ nrm,
                          int* __restrict__ segend, uint* __restrict__ es) {
    int e = blockIdx.x * 256 + threadIdx.x;
    if (e >= E_EDGES) return;
    int bin = dst[e] * R_REL + ety[e];
    int pos = atomicAdd(&segend[bin], 1);
    float n = nrm[e];
    uint q = (uint)fminf(n * 131072.f + 0.5f, 131071.f);
    es[pos] = ((uint)src[e] << 17) | q;
}

// ---------------- combined pre-pack + segend zero + gather (one dispatch) -------
__device__ __forceinline__ void prep_w_body(const float* __restrict__ w,
                                            ushort* __restrict__ wfrag, int t) {
    int lane = t & 63, f = t >> 6;
    int ot = f & 1, rb = f >> 1;              // rb = r*8+b
    int kbase = (lane >> 4) * 8, n = ot * 16 + (lane & 15);
    ushort hv[8], lv[8];
#pragma unroll
    for (int j = 0; j < 8; j++) {
        float x = w[(size_t)(rb * 32 + kbase + j) * 32 + n];
        ushort h = f2bf(x);
        ushort l = f2bf(x - bf2f(h));
        hv[j] = h; lv[j] = l;
    }
    *reinterpret_cast<short8*>(wfrag + ((size_t)(f * 2 + 0) * 64 + lane) * 8) =
        *reinterpret_cast<short8*>(hv);
    *reinterpret_cast<short8*>(wfrag + ((size_t)(f * 2 + 1) * 64 + lane) * 8) =
        *reinterpret_cast<short8*>(lv);
}

__device__ __forceinline__ void prep_lw_body(const float* __restrict__ lw,
                                             ushort* __restrict__ lwfrag, int t) {
    int lane = t & 63, g = t >> 6;
    int kt = g >> 4, ot = g & 15;
    int kbase = kt * 32 + (lane >> 4) * 8, n = ot * 16 + (lane & 15);
    ushort hv[8], lv[8];
#pragma unroll
    for (int j = 0; j < 8; j++) {
        float x = lw[(size_t)(kbase + j) * H_DIM + n];
        ushort h = f2bf(x);
        ushort l = f2bf(x - bf2f(h));
        hv[j] = h; lv[j] = l;
    }
    *reinterpret_cast<short8*>(lwfrag + ((size_t)(g * 2 + 0) * 64 + lane) * 8) =
        *reinterpret_cast<short8*>(hv);
    *reinterpret_cast<short8*>(lwfrag + ((size_t)(g * 2 + 1) * 64 + lane) * 8) =
        *reinterpret_cast<short8*>(lv);
}

__device__ __forceinline__ void prep_fc1_body(const float* __restrict__ w,
                                              ushort* __restrict__ wfrag, int t) {
    int lane = t & 63, g = t >> 6;
    int kt = g >> 5, ot = g & 31;
    int kbase = kt * 32 + (lane >> 4) * 8, n = ot * 16 + (lane & 15);
    ushort hv[8], lv[8];
#pragma unroll
    for (int j = 0; j < 8; j++) {
        float x = w[(size_t)(kbase + j) * D2 + n];
        ushort h = f2bf(x);
        ushort l = f2bf(x - bf2f(h));
        hv[j] = h; lv[j] = l;
    }
    *reinterpret_cast<short8*>(wfrag + ((size_t)(g * 2 + 0) * 64 + lane) * 8) =
        *reinterpret_cast<short8*>(hv);
    *reinterpret_cast<short8*>(wfrag + ((size_t)(g * 2 + 1) * 64 + lane) * 8) =
        *reinterpret_cast<short8*>(lv);
}

#define ZBLOCKS ((NBINS + 255) / 256)       // 1250
#define GBLOCKS 5000                        // gather: 20000 nodes * 64 f16x4 slots
#define PREP_GRID (320 + ZBLOCKS + GBLOCKS)

__global__ void k_prep_all(const float* __restrict__ w1, const float* __restrict__ w2,
                           const float* __restrict__ lw1, const float* __restrict__ lw2,
                           const float* __restrict__ fc1W,
                           const float* __restrict__ emb, const int* __restrict__ nid,
                           ushort* __restrict__ wfrag1, ushort* __restrict__ wfrag2,
                           ushort* __restrict__ lwfrag1, ushort* __restrict__ lwfrag2,
                           ushort* __restrict__ fc1frag, int* __restrict__ segend,
                           _Float16* __restrict__ h0) {
    int b = blockIdx.x, tid = threadIdx.x;
    if (b < 64)        prep_w_body(w1, wfrag1, b * 256 + tid);
    else if (b < 128)  prep_w_body(w2, wfrag2, (b - 64) * 256 + tid);
    else if (b < 160)  prep_lw_body(lw1, lwfrag1, (b - 128) * 256 + tid);
    else if (b < 192)  prep_lw_body(lw2, lwfrag2, (b - 160) * 256 + tid);
    else if (b < 320)  prep_fc1_body(fc1W, fc1frag, (b - 192) * 256 + tid);
    else if (b < 320 + ZBLOCKS) {
        int i = (b - 320) * 256 + tid;
        if (i < NBINS) segend[i] = 0;
    } else {
        int t = (b - 320 - ZBLOCKS) * 256 + tid;
        int node = t >> 6, c = (t & 63) << 2;
        if (node < N_SUBN) {
            const float4 s = *reinterpret_cast<const float4*>(
                emb + (size_t)nid[node] * H_DIM + c);
            half4 d = {(_Float16)s.x, (_Float16)s.y, (_Float16)s.z, (_Float16)s.w};
            *reinterpret_cast<half4*>(h0 + (size_t)node * H_DIM + c) = d;
        }
    }
}

// ---------------- fused RGCN-BDD layer (MFMA, bf16 hi/lo 3-term) ----------------
// Round-11 structure (TILE 32, 512 thr = 8 waves, LDS edge cache, single agg
// buffer, 2 barriers/rel, fp16 h) with HALF-WAVE ROW LOADS: one vmem instruction
// covers TWO edges' rows (lanes 0-31 = chain A's row at 16B/lane, lanes 32-63 =
// chain C's). Halves the vmem request count — the measured binding resource
// (r11: bytes/2 -> no change; r13: requests +46% -> +19% time). Validity is
// per-half exec-masked (no wasted fetches). LDS stores are 16B b128 at the same
// chunk-XOR swizzle the MFMA A-reads use (byte-compatible with r11).
__global__ __launch_bounds__(512) void k_layer(
    const _Float16* __restrict__ hin, const uint* __restrict__ es,
    const int* __restrict__ segend,
    const ushort* __restrict__ wfrag, const ushort* __restrict__ lwfrag,
    const float* __restrict__ bias, _Float16* __restrict__ hout) {
    __shared__ __align__(16) ushort aggH[TILE_N * H_DIM];
    __shared__ __align__(16) ushort aggLo[TILE_N * H_DIM];
    __shared__ int lofs[TILE_N * R_REL + 1];
    __shared__ uint les[ECAP];
    char* cH = (char*)aggH;
    char* cL = (char*)aggLo;
    const int n0 = blockIdx.x * TILE_N;
    const int tid = threadIdx.x;
    const int lane = tid & 63, wv = tid >> 6;
    const int col = lane & 15, kg = lane >> 4;
    const short8* wf  = (const short8*)wfrag;
    const short8* lwf = (const short8*)lwfrag;
    const int t0 = 4 * wv;
    const bool loHalf = lane < 32;
    const int l31 = lane & 31;
    const uint elemoff = (uint)(l31 << 3);      // 8 fp16 per lane (16B)

    {   // block-local offset table (coalesced, once)
        const int base = n0 * R_REL;
        for (int j = tid; j < TILE_N * R_REL + 1; j += 512) {
            int g = base + j - 1;
            lofs[j] = (g < 0) ? 0 : segend[g];
        }
    }
    __syncthreads();
    const int ebase = lofs[0];
    const int elim  = min(lofs[TILE_N * R_REL] - ebase, ECAP);
    for (int j = tid; j < elim; j += 512) les[j] = es[ebase + j];
    __syncthreads();   // les published

    auto eget = [&](int e) -> uint {
        int i = e - ebase;
        return (i < ECAP) ? les[i] : es[e];
    };
    // split 8 f32 (two float4) to bf16 hi/lo and store 16B each at row t, chunk l31
    auto split_store8 = [&](const float4& p, const float4& q, int t) {
        short8 hv, lv; ushort h;
        h = f2bf(p.x); hv[0] = (short)h; lv[0] = (short)f2bf(p.x - bf2f(h));
        h = f2bf(p.y); hv[1] = (short)h; lv[1] = (short)f2bf(p.y - bf2f(h));
        h = f2bf(p.z); hv[2] = (short)h; lv[2] = (short)f2bf(p.z - bf2f(h));
        h = f2bf(p.w); hv[3] = (short)h; lv[3] = (short)f2bf(p.w - bf2f(h));
        h = f2bf(q.x); hv[4] = (short)h; lv[4] = (short)f2bf(q.x - bf2f(h));
        h = f2bf(q.y); hv[5] = (short)h; lv[5] = (short)f2bf(q.y - bf2f(h));
        h = f2bf(q.z); hv[6] = (short)h; lv[6] = (short)f2bf(q.z - bf2f(h));
        h = f2bf(q.w); hv[7] = (short)h; lv[7] = (short)f2bf(q.w - bf2f(h));
        uint byte = (uint)(t * 512) + ((uint)((l31 ^ (t & 7)) << 4));
        *(short8*)(cH + byte) = hv;
        *(short8*)(cL + byte) = lv;
    };

    f32x4 acc[2][2];
#pragma unroll
    for (int mt = 0; mt < 2; ++mt)
#pragma unroll
        for (int ot = 0; ot < 2; ++ot) acc[mt][ot] = (f32x4){0.f, 0.f, 0.f, 0.f};

    for (int r = 0; r < R_REL; ++r) {
        __syncthreads();   // previous MFMA reads done before agg overwrite
        int e0 = lofs[(t0 + 0) * R_REL + r], d0 = lofs[(t0 + 0) * R_REL + r + 1];
        int e1 = lofs[(t0 + 1) * R_REL + r], d1 = lofs[(t0 + 1) * R_REL + r + 1];
        int e2 = lofs[(t0 + 2) * R_REL + r], d2 = lofs[(t0 + 2) * R_REL + r + 1];
        int e3 = lofs[(t0 + 3) * R_REL + r], d3 = lofs[(t0 + 3) * R_REL + r + 1];
        // accA = node (t0 | t0+2) cols l31*8..+8 ; accB = node (t0+1 | t0+3)
        float4 aA0 = make_float4(0.f, 0.f, 0.f, 0.f);
        float4 aA1 = make_float4(0.f, 0.f, 0.f, 0.f);
        float4 aB0 = make_float4(0.f, 0.f, 0.f, 0.f);
        float4 aB1 = make_float4(0.f, 0.f, 0.f, 0.f);
        while ((e0 < d0) | (e1 < d1) | (e2 < d2) | (e3 < d3)) {
            bool g0 = e0 < d0, g1 = e1 < d1, g2 = e2 < d2, g3 = e3 < d3;
            bool gA = loHalf ? g0 : g2;
            bool gB = loHalf ? g1 : g3;
            int  eA = loHalf ? e0 : e2;
            int  eB = loHalf ? e1 : e3;
            uint wA = 0, wB = 0;
            half8 xA = {}, xB = {};
            if (gA) {
                wA = eget(eA);
                xA = *reinterpret_cast<const half8*>(
                    hin + (size_t)(wA >> 17) * H_DIM + elemoff);
            }
            if (gB) {
                wB = eget(eB);
                xB = *reinterpret_cast<const half8*>(
                    hin + (size_t)(wB >> 17) * H_DIM + elemoff);
            }
            float nA = gA ? (float)(wA & 0x1FFFFu) * (1.f / 131072.f) : 0.f;
            float nB = gB ? (float)(wB & 0x1FFFFu) * (1.f / 131072.f) : 0.f;
            aA0.x = fmaf((float)xA[0], nA, aA0.x);
            aA0.y = fmaf((float)xA[1], nA, aA0.y);
            aA0.z = fmaf((float)xA[2], nA, aA0.z);
            aA0.w = fmaf((float)xA[3], nA, aA0.w);
            aA1.x = fmaf((float)xA[4], nA, aA1.x);
            aA1.y = fmaf((float)xA[5], nA, aA1.y);
            aA1.z = fmaf((float)xA[6], nA, aA1.z);
            aA1.w = fmaf((float)xA[7], nA, aA1.w);
            aB0.x = fmaf((float)xB[0], nB, aB0.x);
            aB0.y = fmaf((float)xB[1], nB, aB0.y);
            aB0.z = fmaf((float)xB[2], nB, aB0.z);
            aB0.w = fmaf((float)xB[3], nB, aB0.w);
            aB1.x = fmaf((float)xB[4], nB, aB1.x);
            aB1.y = fmaf((float)xB[5], nB, aB1.y);
            aB1.z = fmaf((float)xB[6], nB, aB1.z);
            aB1.w = fmaf((float)xB[7], nB, aB1.w);
            e0 += g0; e1 += g1; e2 += g2; e3 += g3;
        }
        // ---- store: accA -> row t0+(0|2), accB -> row t0+(1|3) ----
        split_store8(aA0, aA1, t0 + (loHalf ? 0 : 2));
        split_store8(aB0, aB1, t0 + (loHalf ? 1 : 3));
        __syncthreads();   // agg stores visible
        // ---- transform rel r: wave wv owns b-block wv ----
#pragma unroll
        for (int ot = 0; ot < 2; ++ot) {
            int f = (r * 8 + wv) * 2 + ot;
            short8 Bh = wf[(f * 2 + 0) * 64 + lane];
            short8 Bl = wf[(f * 2 + 1) * 64 + lane];
#pragma unroll
            for (int mt = 0; mt < 2; ++mt) {
                int row = mt * 16 + col;
                uint ab = (uint)(row * 512) + ((uint)((wv * 4 + kg) ^ (row & 7)) << 4);
                short8 Ah = *(const short8*)(cH + ab);
                short8 Al = *(const short8*)(cL + ab);
                f32x4 a = acc[mt][ot];
                a = __builtin_amdgcn_mfma_f32_16x16x32_bf16(Ah, Bh, a, 0, 0, 0);
                a = __builtin_amdgcn_mfma_f32_16x16x32_bf16(Ah, Bl, a, 0, 0, 0);
                a = __builtin_amdgcn_mfma_f32_16x16x32_bf16(Al, Bh, a, 0, 0, 0);
                acc[mt][ot] = a;
            }
        }
    }

    // ---- self-loop: restage h tile (2 half-wave loads), K=256 MFMA sweep ----
    __syncthreads();
#pragma unroll
    for (int i = 0; i < 2; ++i) {
        int tS = t0 + (loHalf ? i : i + 2);
        half8 v = *reinterpret_cast<const half8*>(
            hin + (size_t)(n0 + tS) * H_DIM + elemoff);
        float4 p = make_float4((float)v[0], (float)v[1], (float)v[2], (float)v[3]);
        float4 q = make_float4((float)v[4], (float)v[5], (float)v[6], (float)v[7]);
        split_store8(p, q, tS);
    }
    __syncthreads();
#pragma unroll
    for (int kt = 0; kt < 8; ++kt) {
#pragma unroll
        for (int ot = 0; ot < 2; ++ot) {
            int g = kt * 16 + 2 * wv + ot;
            short8 Bh = lwf[(g * 2 + 0) * 64 + lane];
            short8 Bl = lwf[(g * 2 + 1) * 64 + lane];
#pragma unroll
            for (int mt = 0; mt < 2; ++mt) {
                int row = mt * 16 + col;
                uint ab = (uint)(row * 512) + ((uint)((kt * 4 + kg) ^ (row & 7)) << 4);
                short8 Ah = *(const short8*)(cH + ab);
                short8 Al = *(const short8*)(cL + ab);
                f32x4 a = acc[mt][ot];
                a = __builtin_amdgcn_mfma_f32_16x16x32_bf16(Ah, Bh, a, 0, 0, 0);
                a = __builtin_amdgcn_mfma_f32_16x16x32_bf16(Ah, Bl, a, 0, 0, 0);
                a = __builtin_amdgcn_mfma_f32_16x16x32_bf16(Al, Bh, a, 0, 0, 0);
                acc[mt][ot] = a;
            }
        }
    }

    // ---- epilogue: C/D layout col=lane&15, row=(lane>>4)*4+reg; fp16 store ----
#pragma unroll
    for (int mt = 0; mt < 2; ++mt) {
        int nbase = n0 + mt * 16 + kg * 4;
#pragma unroll
        for (int ot = 0; ot < 2; ++ot) {
            int o = 32 * wv + ot * 16 + col;
            float bo = bias[o];
#pragma unroll
            for (int rg = 0; rg < 4; ++rg)
                hout[(size_t)(nbase + rg) * H_DIM + o] = (_Float16)(acc[mt][ot][rg] + bo);
        }
    }
}

// ---------------- fused concat + fc1(MFMA) + relu + fc2 + sigmoid ----------------
__global__ __launch_bounds__(512) void k_mlp(
    const _Float16* __restrict__ h, const int* __restrict__ drugs,
    const int* __restrict__ targets,
    const ushort* __restrict__ fc1frag, const float* __restrict__ b1f,
    const float* __restrict__ W2, const float* __restrict__ b2f,
    float* __restrict__ outp) {
    __shared__ __align__(16) ushort xH[16 * D2];
    __shared__ __align__(16) ushort xL[16 * D2];
    __shared__ float red[16][8];
    char* cH = (char*)xH;
    char* cL = (char*)xL;
    const int tid = threadIdx.x;
    const int lane = tid & 63, wv = tid >> 6;
    const int col = lane & 15, kg = lane >> 4;
    const int p0 = blockIdx.x * 16;
    const short8* wf = (const short8*)fc1frag;

    {   // stage X = [h[drug] | h[target]] (fp16) as bf16 hi/lo, swizzled
        int p = tid >> 5;
        int cc = (tid & 31) * 16;
        int di = drugs[p0 + p], ti = targets[p0 + p];
        const _Float16* srcp = (cc < H_DIM) ? (h + (size_t)di * H_DIM + cc)
                                            : (h + (size_t)ti * H_DIM + (cc - H_DIM));
#pragma unroll
        for (int j = 0; j < 2; ++j) {
            half8 v = *reinterpret_cast<const half8*>(srcp + j * 8);
            float f[8];
#pragma unroll
            for (int q = 0; q < 8; ++q) f[q] = (float)v[q];
            short8 hv, lv;
#pragma unroll
            for (int q = 0; q < 8; ++q) {
                ushort hh = f2bf(f[q]);
                hv[q] = (short)hh;
                lv[q] = (short)f2bf(f[q] - bf2f(hh));
            }
            uint chunk = (uint)((tid & 31) * 2 + j);
            uint byte = (uint)p * 1024 + ((chunk ^ (uint)(p & 7)) << 4);
            *(short8*)(cH + byte) = hv;
            *(short8*)(cL + byte) = lv;
        }
    }
    __syncthreads();

    f32x4 acc[4];
#pragma unroll
    for (int oi = 0; oi < 4; ++oi) acc[oi] = (f32x4){0.f, 0.f, 0.f, 0.f};

    for (int kt = 0; kt < 16; ++kt) {
        uint ab = (uint)col * 1024 + ((uint)((kt * 4 + kg) ^ (col & 7)) << 4);
        short8 Ah = *(const short8*)(cH + ab);
        short8 Al = *(const short8*)(cL + ab);
#pragma unroll
        for (int oi = 0; oi < 4; ++oi) {
            int g = kt * 32 + wv * 4 + oi;
            short8 Bh = wf[(g * 2 + 0) * 64 + lane];
            short8 Bl = wf[(g * 2 + 1) * 64 + lane];
            f32x4 a = acc[oi];
            a = __builtin_amdgcn_mfma_f32_16x16x32_bf16(Ah, Bh, a, 0, 0, 0);
            a = __builtin_amdgcn_mfma_f32_16x16x32_bf16(Ah, Bl, a, 0, 0, 0);
            a = __builtin_amdgcn_mfma_f32_16x16x32_bf16(Al, Bh, a, 0, 0, 0);
            a = __builtin_amdgcn_mfma_f32_16x16x32_bf16(Al, Bl, a, 0, 0, 0);
            acc[oi] = a;
        }
    }

    float val[4] = {0.f, 0.f, 0.f, 0.f};
#pragma unroll
    for (int oi = 0; oi < 4; ++oi) {
        int o = 64 * wv + oi * 16 + col;
        float b1o = b1f[o], w2o = W2[o];
#pragma unroll
        for (int rg = 0; rg < 4; ++rg) {
            float y = acc[oi][rg] + b1o;
            y = y > 0.f ? y : 0.f;
            val[rg] = fmaf(y, w2o, val[rg]);
        }
    }
#pragma unroll
    for (int rg = 0; rg < 4; ++rg) {
        float v = val[rg];
        v += __shfl_xor(v, 1, 64);
        v += __shfl_xor(v, 2, 64);
        v += __shfl_xor(v, 4, 64);
        v += __shfl_xor(v, 8, 64);
        val[rg] = v;
    }
    if (col == 0) {
#pragma unroll
        for (int rg = 0; rg < 4; ++rg) red[kg * 4 + rg][wv] = val[rg];
    }
    __syncthreads();
    if (tid < 16) {
        float s = 0.f;
#pragma unroll
        for (int w = 0; w < 8; w++) s += red[tid][w];
        s += b2f[0];
        outp[p0 + tid] = 1.f / (1.f + __expf(-s));
    }
}

extern "C" void kernel_launch(void* const* d_in, const int* in_sizes, int n_in,
                              void* d_out, int out_size, void* d_ws, size_t ws_size,
                              hipStream_t stream) {
    (void)in_sizes; (void)n_in; (void)out_size; (void)ws_size;
    const int*   drugs   = (const int*)d_in[0];
    const int*   targets = (const int*)d_in[1];
    const int*   nid     = (const int*)d_in[2];
    const int*   src     = (const int*)d_in[3];
    const int*   dst     = (const int*)d_in[4];
    const int*   ety     = (const int*)d_in[5];
    const float* nrm     = (const float*)d_in[6];
    const float* emb     = (const float*)d_in[7];
    const float* w1      = (const float*)d_in[8];
    const float* lw1     = (const float*)d_in[9];
    const float* b1      = (const float*)d_in[10];
    const float* w2      = (const float*)d_in[11];
    const float* lw2     = (const float*)d_in[12];
    const float* b2      = (const float*)d_in[13];
    const float* fc1W    = (const float*)d_in[14];
    const float* fc1b    = (const float*)d_in[15];
    const float* fc2W    = (const float*)d_in[16];
    const float* fc2b    = (const float*)d_in[17];
    float* outp = (float*)d_out;

    // ws layout — same offsets as rounds 10-13.
    char* ws = (char*)d_ws;
    ushort*   wfrag1  = (ushort*)  (ws);                 //    524,288
    ushort*   wfrag2  = (ushort*)  (ws + 524288);        //    524,288
    ushort*   lwfrag1 = (ushort*)  (ws + 1048576);       //    262,144
    ushort*   lwfrag2 = (ushort*)  (ws + 1310720);       //    262,144
    ushort*   fc1frag = (ushort*)  (ws + 1572864);       //  1,048,576
    _Float16* hA      = (_Float16*)(ws + 2621440);       // 10,240,000 used
    _Float16* hB      = (_Float16*)(ws + 23101440);      // 10,240,000 used
    int*      segend  = (int*)     (ws + 43581440);      //  1,280,000
    int*      bs      = (int*)     (ws + 44861440);      //      1,024
    uint*     es      = (uint*)    (ws + 44862464);      //  1,600,000 -> end 46,462,464

    k_prep_all<<<PREP_GRID, 256, 0, stream>>>(w1, w2, lw1, lw2, fc1W, emb, nid,
                                              wfrag1, wfrag2, lwfrag1, lwfrag2,
                                              fc1frag, segend, hA);
    k_count  <<<(E_EDGES + 255) / 256, 256, 0, stream>>>(dst, ety, segend);
    k_scan1  <<<NSCAN_BLOCKS, 256, 0, stream>>>(segend, bs);
    k_scan2  <<<1, 256, 0, stream>>>(bs);
    k_scan3  <<<(NBINS + 255) / 256, 256, 0, stream>>>(segend, bs);
    k_scatter<<<(E_EDGES + 255) / 256, 256, 0, stream>>>(src, dst, ety, nrm, segend, es);
    k_layer  <<<NT_BLOCKS, 512, 0, stream>>>(hA, es, segend, wfrag1, lwfrag1, b1, hB);
    k_layer  <<<NT_BLOCKS, 512, 0, stream>>>(hB, es, segend, wfrag2, lwfrag2, b2, hA);
    k_mlp    <<<NPAIRS / 16, 512, 0, stream>>>(hA, drugs, targets, fc1frag, fc1b, fc2W, fc2b, outp);
}

// Round 15
// 265.073 us; speedup vs baseline: 1.2552x; 1.2552x over previous
//
#include <hip/hip_runtime.h>
#include <math.h>

typedef __attribute__((ext_vector_type(8))) short short8;
typedef __attribute__((ext_vector_type(4))) float f32x4;
typedef __attribute__((ext_vector_type(4))) _Float16 half4;
typedef __attribute__((ext_vector_type(8))) _Float16 half8;

#define N_SUBN   20000
#define E_EDGES  400000
#define R_REL    16
#define H_DIM    256
#define NBINS    (N_SUBN * R_REL)          // 320000 (dst,rel) buckets
#define SCAN_CHUNK 2048
#define NSCAN_BLOCKS ((NBINS + SCAN_CHUNK - 1) / SCAN_CHUNK)   // 157
#define NPAIRS   4096
#define TILE_N   32
#define NT_BLOCKS (N_SUBN / TILE_N)                            // 625 exact
#define D2       512
#define ECAP     1024                      // LDS edge-cache capacity (avg ~640/block)

// ---- bf16 hi/lo split helpers (RNE) ----
__device__ __forceinline__ ushort f2bf(float x) {
    uint u = __float_as_uint(x);
    u += 0x7fffu + ((u >> 16) & 1u);
    return (ushort)(u >> 16);
}
__device__ __forceinline__ float bf2f(ushort h) {
    return __uint_as_float(((uint)h) << 16);
}

// ---------------- CSR build over bin = dst*R + etype ----------------
__global__ void k_count(const int* __restrict__ dst, const int* __restrict__ ety,
                        int* __restrict__ cnt) {
    int e = blockIdx.x * 256 + threadIdx.x;
    if (e < E_EDGES) atomicAdd(&cnt[dst[e] * R_REL + ety[e]], 1);
}

__global__ void k_scan1(int* __restrict__ data, int* __restrict__ bs) {
    __shared__ int ts[256];
    int base = blockIdx.x * SCAN_CHUNK + threadIdx.x * 8;
    int v[8]; int s = 0;
#pragma unroll
    for (int j = 0; j < 8; j++) {
        int idx = base + j;
        v[j] = (idx < NBINS) ? data[idx] : 0;
        s += v[j];
    }
    ts[threadIdx.x] = s;
    __syncthreads();
    for (int off = 1; off < 256; off <<= 1) {
        int add = (threadIdx.x >= (unsigned)off) ? ts[threadIdx.x - off] : 0;
        __syncthreads();
        ts[threadIdx.x] += add;
        __syncthreads();
    }
    int excl = ts[threadIdx.x] - s;
    if (threadIdx.x == 255) bs[blockIdx.x] = ts[255];
    int run = excl;
#pragma unroll
    for (int j = 0; j < 8; j++) {
        int idx = base + j;
        if (idx < NBINS) data[idx] = run;
        run += v[j];
    }
}

__global__ void k_scan2(int* __restrict__ bs) {
    __shared__ int ls[NSCAN_BLOCKS];
    if (threadIdx.x < NSCAN_BLOCKS) ls[threadIdx.x] = bs[threadIdx.x];
    __syncthreads();
    if (threadIdx.x == 0) {
        int run = 0;
        for (int i = 0; i < NSCAN_BLOCKS; i++) { int t = ls[i]; ls[i] = run; run += t; }
    }
    __syncthreads();
    if (threadIdx.x < NSCAN_BLOCKS) bs[threadIdx.x] = ls[threadIdx.x];
}

__global__ void k_scan3(int* __restrict__ data, const int* __restrict__ bs) {
    int idx = blockIdx.x * 256 + threadIdx.x;
    if (idx < NBINS) data[idx] = data[idx] + bs[idx / SCAN_CHUNK];
}

// scatter increments segend in place: post-scatter segend[bin] = END of bin,
// beg(bin) = (bin==0) ? 0 : segend[bin-1]. Edge packed: (src<<17) | norm_q17.
__global__ void k_scatter(const int* __restrict__ src, const int* __restrict__ dst,
                          const int* __restrict__ ety, const float* __restrict__ nrm,
                          int* __restrict__ segend, uint* __restrict__ es) {
    int e = blockIdx.x * 256 + threadIdx.x;
    if (e >= E_EDGES) return;
    int bin = dst[e] * R_REL + ety[e];
    int pos = atomicAdd(&segend[bin], 1);
    float n = nrm[e];
    uint q = (uint)fminf(n * 131072.f + 0.5f, 131071.f);
    es[pos] = ((uint)src[e] << 17) | q;
}

// ---------------- combined pre-pack + segend zero + gather (one dispatch) -------
__device__ __forceinline__ void prep_w_body(const float* __restrict__ w,
                                            ushort* __restrict__ wfrag, int t) {
    int lane = t & 63, f = t >> 6;
    int ot = f & 1, rb = f >> 1;              // rb = r*8+b
    int kbase = (lane >> 4) * 8, n = ot * 16 + (lane & 15);
    ushort hv[8], lv[8];
#pragma unroll
    for (int j = 0; j < 8; j++) {
        float x = w[(size_t)(rb * 32 + kbase + j) * 32 + n];
        ushort h = f2bf(x);
        ushort l = f2bf(x - bf2f(h));
        hv[j] = h; lv[j] = l;
    }
    *reinterpret_cast<short8*>(wfrag + ((size_t)(f * 2 + 0) * 64 + lane) * 8) =
        *reinterpret_cast<short8*>(hv);
    *reinterpret_cast<short8*>(wfrag + ((size_t)(f * 2 + 1) * 64 + lane) * 8) =
        *reinterpret_cast<short8*>(lv);
}

__device__ __forceinline__ void prep_lw_body(const float* __restrict__ lw,
                                             ushort* __restrict__ lwfrag, int t) {
    int lane = t & 63, g = t >> 6;
    int kt = g >> 4, ot = g & 15;
    int kbase = kt * 32 + (lane >> 4) * 8, n = ot * 16 + (lane & 15);
    ushort hv[8], lv[8];
#pragma unroll
    for (int j = 0; j < 8; j++) {
        float x = lw[(size_t)(kbase + j) * H_DIM + n];
        ushort h = f2bf(x);
        ushort l = f2bf(x - bf2f(h));
        hv[j] = h; lv[j] = l;
    }
    *reinterpret_cast<short8*>(lwfrag + ((size_t)(g * 2 + 0) * 64 + lane) * 8) =
        *reinterpret_cast<short8*>(hv);
    *reinterpret_cast<short8*>(lwfrag + ((size_t)(g * 2 + 1) * 64 + lane) * 8) =
        *reinterpret_cast<short8*>(lv);
}

__device__ __forceinline__ void prep_fc1_body(const float* __restrict__ w,
                                              ushort* __restrict__ wfrag, int t) {
    int lane = t & 63, g = t >> 6;
    int kt = g >> 5, ot = g & 31;
    int kbase = kt * 32 + (lane >> 4) * 8, n = ot * 16 + (lane & 15);
    ushort hv[8], lv[8];
#pragma unroll
    for (int j = 0; j < 8; j++) {
        float x = w[(size_t)(kbase + j) * D2 + n];
        ushort h = f2bf(x);
        ushort l = f2bf(x - bf2f(h));
        hv[j] = h; lv[j] = l;
    }
    *reinterpret_cast<short8*>(wfrag + ((size_t)(g * 2 + 0) * 64 + lane) * 8) =
        *reinterpret_cast<short8*>(hv);
    *reinterpret_cast<short8*>(wfrag + ((size_t)(g * 2 + 1) * 64 + lane) * 8) =
        *reinterpret_cast<short8*>(lv);
}

#define ZBLOCKS ((NBINS + 255) / 256)       // 1250
#define GBLOCKS 5000                        // gather: 20000 nodes * 64 f16x4 slots
#define PREP_GRID (320 + ZBLOCKS + GBLOCKS)

__global__ void k_prep_all(const float* __restrict__ w1, const float* __restrict__ w2,
                           const float* __restrict__ lw1, const float* __restrict__ lw2,
                           const float* __restrict__ fc1W,
                           const float* __restrict__ emb, const int* __restrict__ nid,
                           ushort* __restrict__ wfrag1, ushort* __restrict__ wfrag2,
                           ushort* __restrict__ lwfrag1, ushort* __restrict__ lwfrag2,
                           ushort* __restrict__ fc1frag, int* __restrict__ segend,
                           _Float16* __restrict__ h0) {
    int b = blockIdx.x, tid = threadIdx.x;
    if (b < 64)        prep_w_body(w1, wfrag1, b * 256 + tid);
    else if (b < 128)  prep_w_body(w2, wfrag2, (b - 64) * 256 + tid);
    else if (b < 160)  prep_lw_body(lw1, lwfrag1, (b - 128) * 256 + tid);
    else if (b < 192)  prep_lw_body(lw2, lwfrag2, (b - 160) * 256 + tid);
    else if (b < 320)  prep_fc1_body(fc1W, fc1frag, (b - 192) * 256 + tid);
    else if (b < 320 + ZBLOCKS) {
        int i = (b - 320) * 256 + tid;
        if (i < NBINS) segend[i] = 0;
    } else {
        int t = (b - 320 - ZBLOCKS) * 256 + tid;
        int node = t >> 6, c = (t & 63) << 2;
        if (node < N_SUBN) {
            const float4 s = *reinterpret_cast<const float4*>(
                emb + (size_t)nid[node] * H_DIM + c);
            half4 d = {(_Float16)s.x, (_Float16)s.y, (_Float16)s.z, (_Float16)s.w};
            *reinterpret_cast<half4*>(h0 + (size_t)node * H_DIM + c) = d;
        }
    }
}

// ---------------- fused RGCN-BDD layer (MFMA, bf16 hi/lo 3-term) ----------------
// ROUND-11 WINNER, verbatim: TILE 32, 512 thr = 8 waves, wave owns 4 nodes via
// 4 interleaved edge cursors, block-level LDS edge cache, single agg buffer,
// 2 barriers/rel, fp16 h storage (f32 accumulation in registers).
// k_layer = ~102 us/layer. Six structural variants (dbuf, coop-fetch, split-
// tile, cross-MFMA prefetch, batched-branchless, half-wave loads) all regressed:
// the kernel sits at the overlap floor of {VALU agg work, load latency, MFMA}.
__global__ __launch_bounds__(512) void k_layer(
    const _Float16* __restrict__ hin, const uint* __restrict__ es,
    const int* __restrict__ segend,
    const ushort* __restrict__ wfrag, const ushort* __restrict__ lwfrag,
    const float* __restrict__ bias, _Float16* __restrict__ hout) {
    __shared__ __align__(16) ushort aggH[TILE_N * H_DIM];
    __shared__ __align__(16) ushort aggLo[TILE_N * H_DIM];
    __shared__ int lofs[TILE_N * R_REL + 1];
    __shared__ uint les[ECAP];
    char* cH = (char*)aggH;
    char* cL = (char*)aggLo;
    const int n0 = blockIdx.x * TILE_N;
    const int tid = threadIdx.x;
    const int lane = tid & 63, wv = tid >> 6;
    const int col = lane & 15, kg = lane >> 4;
    const short8* wf  = (const short8*)wfrag;
    const short8* lwf = (const short8*)lwfrag;
    const uint laneoff = (uint)(lane << 2);     // element offset (4 fp16 per lane)
    const int t0 = 4 * wv;

    {   // block-local offset table (coalesced, once)
        const int base = n0 * R_REL;
        for (int j = tid; j < TILE_N * R_REL + 1; j += 512) {
            int g = base + j - 1;
            lofs[j] = (g < 0) ? 0 : segend[g];
        }
    }
    __syncthreads();
    const int ebase = lofs[0];
    const int elim  = min(lofs[TILE_N * R_REL] - ebase, ECAP);
    for (int j = tid; j < elim; j += 512) les[j] = es[ebase + j];
    // first loop-top __syncthreads() publishes les

    f32x4 acc[2][2];
#pragma unroll
    for (int mt = 0; mt < 2; ++mt)
#pragma unroll
        for (int ot = 0; ot < 2; ++ot) acc[mt][ot] = (f32x4){0.f, 0.f, 0.f, 0.f};

    for (int r = 0; r < R_REL; ++r) {
        __syncthreads();   // les/lofs ready (r=0) / previous MFMA reads done
        // ---- 4-way interleaved aggregation of nodes t0..t0+3 ----
        int e0 = lofs[(t0 + 0) * R_REL + r], d0 = lofs[(t0 + 0) * R_REL + r + 1];
        int e1 = lofs[(t0 + 1) * R_REL + r], d1 = lofs[(t0 + 1) * R_REL + r + 1];
        int e2 = lofs[(t0 + 2) * R_REL + r], d2 = lofs[(t0 + 2) * R_REL + r + 1];
        int e3 = lofs[(t0 + 3) * R_REL + r], d3 = lofs[(t0 + 3) * R_REL + r + 1];
        float4 a0 = make_float4(0.f, 0.f, 0.f, 0.f);
        float4 a1 = make_float4(0.f, 0.f, 0.f, 0.f);
        float4 a2 = make_float4(0.f, 0.f, 0.f, 0.f);
        float4 a3 = make_float4(0.f, 0.f, 0.f, 0.f);
        while ((e0 < d0) | (e1 < d1) | (e2 < d2) | (e3 < d3)) {
            bool g0 = e0 < d0, g1 = e1 < d1, g2 = e2 < d2, g3 = e3 < d3;
            uint p0 = 0, p1 = 0, p2 = 0, p3 = 0;
            if (g0) { int i = e0 - ebase; p0 = (i < ECAP) ? les[i] : es[e0]; ++e0; }
            if (g1) { int i = e1 - ebase; p1 = (i < ECAP) ? les[i] : es[e1]; ++e1; }
            if (g2) { int i = e2 - ebase; p2 = (i < ECAP) ? les[i] : es[e2]; ++e2; }
            if (g3) { int i = e3 - ebase; p3 = (i < ECAP) ? les[i] : es[e3]; ++e3; }
            if (g0) {
                const half4 x = *reinterpret_cast<const half4*>(
                    hin + (size_t)(p0 >> 17) * H_DIM + laneoff);
                float nm = (float)(p0 & 0x1FFFFu) * (1.f / 131072.f);
                a0.x = fmaf((float)x[0], nm, a0.x); a0.y = fmaf((float)x[1], nm, a0.y);
                a0.z = fmaf((float)x[2], nm, a0.z); a0.w = fmaf((float)x[3], nm, a0.w);
            }
            if (g1) {
                const half4 x = *reinterpret_cast<const half4*>(
                    hin + (size_t)(p1 >> 17) * H_DIM + laneoff);
                float nm = (float)(p1 & 0x1FFFFu) * (1.f / 131072.f);
                a1.x = fmaf((float)x[0], nm, a1.x); a1.y = fmaf((float)x[1], nm, a1.y);
                a1.z = fmaf((float)x[2], nm, a1.z); a1.w = fmaf((float)x[3], nm, a1.w);
            }
            if (g2) {
                const half4 x = *reinterpret_cast<const half4*>(
                    hin + (size_t)(p2 >> 17) * H_DIM + laneoff);
                float nm = (float)(p2 & 0x1FFFFu) * (1.f / 131072.f);
                a2.x = fmaf((float)x[0], nm, a2.x); a2.y = fmaf((float)x[1], nm, a2.y);
                a2.z = fmaf((float)x[2], nm, a2.z); a2.w = fmaf((float)x[3], nm, a2.w);
            }
            if (g3) {
                const half4 x = *reinterpret_cast<const half4*>(
                    hin + (size_t)(p3 >> 17) * H_DIM + laneoff);
                float nm = (float)(p3 & 0x1FFFFu) * (1.f / 131072.f);
                a3.x = fmaf((float)x[0], nm, a3.x); a3.y = fmaf((float)x[1], nm, a3.y);
                a3.z = fmaf((float)x[2], nm, a3.z); a3.w = fmaf((float)x[3], nm, a3.w);
            }
        }
#pragma unroll
        for (int i = 0; i < 4; ++i) {
            float4 av = (i == 0) ? a0 : (i == 1) ? a1 : (i == 2) ? a2 : a3;
            int t = t0 + i;
            ushort h0 = f2bf(av.x), h1 = f2bf(av.y), h2 = f2bf(av.z), h3 = f2bf(av.w);
            uint2 ph = make_uint2((uint)h0 | ((uint)h1 << 16), (uint)h2 | ((uint)h3 << 16));
            uint2 pl = make_uint2(
                (uint)f2bf(av.x - bf2f(h0)) | ((uint)f2bf(av.y - bf2f(h1)) << 16),
                (uint)f2bf(av.z - bf2f(h2)) | ((uint)f2bf(av.w - bf2f(h3)) << 16));
            uint byte = (uint)(t * 512) + ((((lane >> 1) ^ (t & 7)) << 4) | ((lane & 1) << 3));
            *(uint2*)(cH + byte) = ph;
            *(uint2*)(cL + byte) = pl;
        }
        __syncthreads();
        // ---- transform: wave wv owns b-block wv ----
#pragma unroll
        for (int ot = 0; ot < 2; ++ot) {
            int f = (r * 8 + wv) * 2 + ot;
            short8 Bh = wf[(f * 2 + 0) * 64 + lane];
            short8 Bl = wf[(f * 2 + 1) * 64 + lane];
#pragma unroll
            for (int mt = 0; mt < 2; ++mt) {
                int row = mt * 16 + col;
                uint ab = (uint)(row * 512) + ((uint)((wv * 4 + kg) ^ (row & 7)) << 4);
                short8 Ah = *(const short8*)(cH + ab);
                short8 Al = *(const short8*)(cL + ab);
                f32x4 a = acc[mt][ot];
                a = __builtin_amdgcn_mfma_f32_16x16x32_bf16(Ah, Bh, a, 0, 0, 0);
                a = __builtin_amdgcn_mfma_f32_16x16x32_bf16(Ah, Bl, a, 0, 0, 0);
                a = __builtin_amdgcn_mfma_f32_16x16x32_bf16(Al, Bh, a, 0, 0, 0);
                acc[mt][ot] = a;
            }
        }
    }

    // ---- self-loop: restage h tile as hi/lo, K=256 MFMA sweep ----
    __syncthreads();
#pragma unroll
    for (int i = 0; i < 4; ++i) {
        int t = t0 + i;
        const half4 xh = *reinterpret_cast<const half4*>(
            hin + (size_t)(n0 + t) * H_DIM + laneoff);
        float4 xv = make_float4((float)xh[0], (float)xh[1], (float)xh[2], (float)xh[3]);
        ushort h0 = f2bf(xv.x), h1 = f2bf(xv.y), h2 = f2bf(xv.z), h3 = f2bf(xv.w);
        uint2 ph = make_uint2((uint)h0 | ((uint)h1 << 16), (uint)h2 | ((uint)h3 << 16));
        uint2 pl = make_uint2(
            (uint)f2bf(xv.x - bf2f(h0)) | ((uint)f2bf(xv.y - bf2f(h1)) << 16),
            (uint)f2bf(xv.z - bf2f(h2)) | ((uint)f2bf(xv.w - bf2f(h3)) << 16));
        uint byte = (uint)(t * 512) + ((((lane >> 1) ^ (t & 7)) << 4) | ((lane & 1) << 3));
        *(uint2*)(cH + byte) = ph;
        *(uint2*)(cL + byte) = pl;
    }
    __syncthreads();
#pragma unroll
    for (int kt = 0; kt < 8; ++kt) {
#pragma unroll
        for (int ot = 0; ot < 2; ++ot) {
            int g = kt * 16 + 2 * wv + ot;
            short8 Bh = lwf[(g * 2 + 0) * 64 + lane];
            short8 Bl = lwf[(g * 2 + 1) * 64 + lane];
#pragma unroll
            for (int mt = 0; mt < 2; ++mt) {
                int row = mt * 16 + col;
                uint ab = (uint)(row * 512) + ((uint)((kt * 4 + kg) ^ (row & 7)) << 4);
                short8 Ah = *(const short8*)(cH + ab);
                short8 Al = *(const short8*)(cL + ab);
                f32x4 a = acc[mt][ot];
                a = __builtin_amdgcn_mfma_f32_16x16x32_bf16(Ah, Bh, a, 0, 0, 0);
                a = __builtin_amdgcn_mfma_f32_16x16x32_bf16(Ah, Bl, a, 0, 0, 0);
                a = __builtin_amdgcn_mfma_f32_16x16x32_bf16(Al, Bh, a, 0, 0, 0);
                acc[mt][ot] = a;
            }
        }
    }

    // ---- epilogue: C/D layout col=lane&15, row=(lane>>4)*4+reg; fp16 store ----
#pragma unroll
    for (int mt = 0; mt < 2; ++mt) {
        int nbase = n0 + mt * 16 + kg * 4;
#pragma unroll
        for (int ot = 0; ot < 2; ++ot) {
            int o = 32 * wv + ot * 16 + col;
            float bo = bias[o];
#pragma unroll
            for (int rg = 0; rg < 4; ++rg)
                hout[(size_t)(nbase + rg) * H_DIM + o] = (_Float16)(acc[mt][ot][rg] + bo);
        }
    }
}

// ---------------- fused concat + fc1(MFMA) + relu + fc2 + sigmoid ----------------
__global__ __launch_bounds__(512) void k_mlp(
    const _Float16* __restrict__ h, const int* __restrict__ drugs,
    const int* __restrict__ targets,
    const ushort* __restrict__ fc1frag, const float* __restrict__ b1f,
    const float* __restrict__ W2, const float* __restrict__ b2f,
    float* __restrict__ outp) {
    __shared__ __align__(16) ushort xH[16 * D2];
    __shared__ __align__(16) ushort xL[16 * D2];
    __shared__ float red[16][8];
    char* cH = (char*)xH;
    char* cL = (char*)xL;
    const int tid = threadIdx.x;
    const int lane = tid & 63, wv = tid >> 6;
    const int col = lane & 15, kg = lane >> 4;
    const int p0 = blockIdx.x * 16;
    const short8* wf = (const short8*)fc1frag;

    {   // stage X = [h[drug] | h[target]] (fp16) as bf16 hi/lo, swizzled
        int p = tid >> 5;
        int cc = (tid & 31) * 16;
        int di = drugs[p0 + p], ti = targets[p0 + p];
        const _Float16* srcp = (cc < H_DIM) ? (h + (size_t)di * H_DIM + cc)
                                            : (h + (size_t)ti * H_DIM + (cc - H_DIM));
#pragma unroll
        for (int j = 0; j < 2; ++j) {
            half8 v = *reinterpret_cast<const half8*>(srcp + j * 8);
            float f[8];
#pragma unroll
            for (int q = 0; q < 8; ++q) f[q] = (float)v[q];
            short8 hv, lv;
#pragma unroll
            for (int q = 0; q < 8; ++q) {
                ushort hh = f2bf(f[q]);
                hv[q] = (short)hh;
                lv[q] = (short)f2bf(f[q] - bf2f(hh));
            }
            uint chunk = (uint)((tid & 31) * 2 + j);
            uint byte = (uint)p * 1024 + ((chunk ^ (uint)(p & 7)) << 4);
            *(short8*)(cH + byte) = hv;
            *(short8*)(cL + byte) = lv;
        }
    }
    __syncthreads();

    f32x4 acc[4];
#pragma unroll
    for (int oi = 0; oi < 4; ++oi) acc[oi] = (f32x4){0.f, 0.f, 0.f, 0.f};

    for (int kt = 0; kt < 16; ++kt) {
        uint ab = (uint)col * 1024 + ((uint)((kt * 4 + kg) ^ (col & 7)) << 4);
        short8 Ah = *(const short8*)(cH + ab);
        short8 Al = *(const short8*)(cL + ab);
#pragma unroll
        for (int oi = 0; oi < 4; ++oi) {
            int g = kt * 32 + wv * 4 + oi;
            short8 Bh = wf[(g * 2 + 0) * 64 + lane];
            short8 Bl = wf[(g * 2 + 1) * 64 + lane];
            f32x4 a = acc[oi];
            a = __builtin_amdgcn_mfma_f32_16x16x32_bf16(Ah, Bh, a, 0, 0, 0);
            a = __builtin_amdgcn_mfma_f32_16x16x32_bf16(Ah, Bl, a, 0, 0, 0);
            a = __builtin_amdgcn_mfma_f32_16x16x32_bf16(Al, Bh, a, 0, 0, 0);
            a = __builtin_amdgcn_mfma_f32_16x16x32_bf16(Al, Bl, a, 0, 0, 0);
            acc[oi] = a;
        }
    }

    float val[4] = {0.f, 0.f, 0.f, 0.f};
#pragma unroll
    for (int oi = 0; oi < 4; ++oi) {
        int o = 64 * wv + oi * 16 + col;
        float b1o = b1f[o], w2o = W2[o];
#pragma unroll
        for (int rg = 0; rg < 4; ++rg) {
            float y = acc[oi][rg] + b1o;
            y = y > 0.f ? y : 0.f;
            val[rg] = fmaf(y, w2o, val[rg]);
        }
    }
#pragma unroll
    for (int rg = 0; rg < 4; ++rg) {
        float v = val[rg];
        v += __shfl_xor(v, 1, 64);
        v += __shfl_xor(v, 2, 64);
        v += __shfl_xor(v, 4, 64);
        v += __shfl_xor(v, 8, 64);
        val[rg] = v;
    }
    if (col == 0) {
#pragma unroll
        for (int rg = 0; rg < 4; ++rg) red[kg * 4 + rg][wv] = val[rg];
    }
    __syncthreads();
    if (tid < 16) {
        float s = 0.f;
#pragma unroll
        for (int w = 0; w < 8; w++) s += red[tid][w];
        s += b2f[0];
        outp[p0 + tid] = 1.f / (1.f + __expf(-s));
    }
}

extern "C" void kernel_launch(void* const* d_in, const int* in_sizes, int n_in,
                              void* d_out, int out_size, void* d_ws, size_t ws_size,
                              hipStream_t stream) {
    (void)in_sizes; (void)n_in; (void)out_size; (void)ws_size;
    const int*   drugs   = (const int*)d_in[0];
    const int*   targets = (const int*)d_in[1];
    const int*   nid     = (const int*)d_in[2];
    const int*   src     = (const int*)d_in[3];
    const int*   dst     = (const int*)d_in[4];
    const int*   ety     = (const int*)d_in[5];
    const float* nrm     = (const float*)d_in[6];
    const float* emb     = (const float*)d_in[7];
    const float* w1      = (const float*)d_in[8];
    const float* lw1     = (const float*)d_in[9];
    const float* b1      = (const float*)d_in[10];
    const float* w2      = (const float*)d_in[11];
    const float* lw2     = (const float*)d_in[12];
    const float* b2      = (const float*)d_in[13];
    const float* fc1W    = (const float*)d_in[14];
    const float* fc1b    = (const float*)d_in[15];
    const float* fc2W    = (const float*)d_in[16];
    const float* fc2b    = (const float*)d_in[17];
    float* outp = (float*)d_out;

    // ws layout — same offsets as rounds 10-14.
    char* ws = (char*)d_ws;
    ushort*   wfrag1  = (ushort*)  (ws);                 //    524,288
    ushort*   wfrag2  = (ushort*)  (ws + 524288);        //    524,288
    ushort*   lwfrag1 = (ushort*)  (ws + 1048576);       //    262,144
    ushort*   lwfrag2 = (ushort*)  (ws + 1310720);       //    262,144
    ushort*   fc1frag = (ushort*)  (ws + 1572864);       //  1,048,576
    _Float16* hA      = (_Float16*)(ws + 2621440);       // 10,240,000 used
    _Float16* hB      = (_Float16*)(ws + 23101440);      // 10,240,000 used
    int*      segend  = (int*)     (ws + 43581440);      //  1,280,000
    int*      bs      = (int*)     (ws + 44861440);      //      1,024
    uint*     es      = (uint*)    (ws + 44862464);      //  1,600,000 -> end 46,462,464

    k_prep_all<<<PREP_GRID, 256, 0, stream>>>(w1, w2, lw1, lw2, fc1W, emb, nid,
                                              wfrag1, wfrag2, lwfrag1, lwfrag2,
                                              fc1frag, segend, hA);
    k_count  <<<(E_EDGES + 255) / 256, 256, 0, stream>>>(dst, ety, segend);
    k_scan1  <<<NSCAN_BLOCKS, 256, 0, stream>>>(segend, bs);
    k_scan2  <<<1, 256, 0, stream>>>(bs);
    k_scan3  <<<(NBINS + 255) / 256, 256, 0, stream>>>(segend, bs);
    k_scatter<<<(E_EDGES + 255) / 256, 256, 0, stream>>>(src, dst, ety, nrm, segend, es);
    k_layer  <<<NT_BLOCKS, 512, 0, stream>>>(hA, es, segend, wfrag1, lwfrag1, b1, hB);
    k_layer  <<<NT_BLOCKS, 512, 0, stream>>>(hB, es, segend, wfrag2, lwfrag2, b2, hA);
    k_mlp    <<<NPAIRS / 16, 512, 0, stream>>>(hA, drugs, targets, fc1frag, fc1b, fc2W, fc2b, outp);
}